// Round 14
// baseline (574.935 us; speedup 1.0000x reference)
//
#include <hip/hip_runtime.h>

// CNF forward: 8 fixed dopri5 steps x 6 stages, rows independent.
// R19: R18's 3-tile spilled; diagnosis refined -- under (256,2) the backend
// splits the unified file at a FIXED 128 arch / 128 acc boundary (R15-R17
// all report exactly 128 despite varying demand; R18's ~200-arch demand
// spilled). Arch is the scarce half; acc has 64 FREE slots (weights=64).
// So: third tile returns with its cold state in the ACC half via explicit
// v_accvgpr_write/read -- kfC[6][4] (24) + ghfC[16] (16) as AGPRs
// (acc 104 <= 128). Unlike R12's failed pin, consumers here are VALU, so
// the accvgpr_read copy per use is the intended move (~38 extra VALU/stage,
// +8% VALU) buying a 3rd independent chain + barriers/row x2/3.
// Rows/CU 64 -> 96. zvC/lppC + transients (~25) are the only arch adds.
// Tripwire: FETCH > 100 MB = arch overflow -> revert to R17 (210us floor).

typedef __bf16 bf16x8 __attribute__((ext_vector_type(8)));
typedef __bf16 bf16x4 __attribute__((ext_vector_type(4)));
typedef float  f32x4  __attribute__((ext_vector_type(4)));
typedef unsigned int u32;

#define MFMA16(a, b, c) __builtin_amdgcn_mfma_f32_16x16x32_bf16((a), (b), (c), 0, 0, 0)

#define SY_S 76    // sY row stride in bf16 (38 dwords == 6 mod 32)
#define SH_S 268   // sH row stride in bf16 (134 dwords == 6 mod 32)

__device__ __forceinline__ float fast_tanh2(float x2) {   // x2 = 2*log2e*x
    float e = __builtin_amdgcn_exp2f(x2);                 // e^(2x)
    return 1.0f - 2.0f * __builtin_amdgcn_rcpf(e + 1.0f);
}
__device__ __forceinline__ bf16x8 cvt8(f32x4 a, f32x4 b) {
    bf16x8 r;
#pragma unroll
    for (int i = 0; i < 4; ++i) { r[i] = (__bf16)a[i]; r[4 + i] = (__bf16)b[i]; }
    return r;
}
// Park a value in the free AGPR half / retrieve it (VALU-consumer pattern).
__device__ __forceinline__ float to_a(float v) {
    float r; asm("v_accvgpr_write_b32 %0, %1" : "=a"(r) : "v"(v)); return r;
}
__device__ __forceinline__ float from_a(float a) {
    float r; asm("v_accvgpr_read_b32 %0, %1" : "=v"(r) : "a"(a)); return r;
}

extern "C" __global__ void __launch_bounds__(256, 2)
cnf_kernel(const float* __restrict__ Yg, const float* __restrict__ Eg,
           const float* __restrict__ W1g, const float* __restrict__ b1g,
           const float* __restrict__ W2g, const float* __restrict__ b2g,
           float* __restrict__ Og)
{
    // ---- LDS (~35.6 KB; 2 blocks/CU at 2 waves/EU) ----
    __shared__ __align__(16) __bf16 sYA[16 * SY_S], sYB[16 * SY_S], sYC[16 * SY_S];
    __shared__ __align__(16) __bf16 sHA[16 * SH_S], sHB[16 * SH_S], sHC[16 * SH_S];
    __shared__ float sBW[256];                      // per-stage (b1 + t*W1_t) * 2log2e
    __shared__ float sRedSS[192], sRedLP[192];

    const int tid  = threadIdx.x;
    const int wave = tid >> 6;        // 0..3
    const int lane = tid & 63;
    const int quad = lane >> 4;
    const int l16  = lane & 15;
    const int colb = wave * 16;       // own output-col tile base
    const int jb   = wave * 64;       // own hidden-j base
    const int rowA = blockIdx.x * 48 + l16;           // tile A batch row
    const int rowB = rowA + 16;                       // tile B batch row
    const int rowC = min(rowA + 32, 32767);           // tile C (clamped in last block)

    const float TS  = 2.885390081777927f;    // 2*log2(e)
    const float IVS = 0.346573590279973f;    // ln(2)/2 = 1/TS

    // ---------------- e fragments (all tiles) ----------------
    bf16x8 aeA0, aeA1, aeB0, aeB1, aeC0, aeC1;
    {
        const float* eA = Eg + rowA * 64;
        const float* eB = Eg + rowB * 64;
        const float* eC = Eg + rowC * 64;
        aeA0 = cvt8(*(const f32x4*)(eA + quad * 8),      *(const f32x4*)(eA + quad * 8 + 4));
        aeA1 = cvt8(*(const f32x4*)(eA + 32 + quad * 8), *(const f32x4*)(eA + 32 + quad * 8 + 4));
        aeB0 = cvt8(*(const f32x4*)(eB + quad * 8),      *(const f32x4*)(eB + quad * 8 + 4));
        aeB1 = cvt8(*(const f32x4*)(eB + 32 + quad * 8), *(const f32x4*)(eB + 32 + quad * 8 + 4));
        aeC0 = cvt8(*(const f32x4*)(eC + quad * 8),      *(const f32x4*)(eC + quad * 8 + 4));
        aeC1 = cvt8(*(const f32x4*)(eC + 32 + quad * 8), *(const f32x4*)(eC + 32 + quad * 8 + 4));
    }

    // ---------------- W1 fragments, PRE-SCALED by TS (A-op: [m=j][k=d]) ----
    bf16x8 w1f[8];
#pragma unroll
    for (int t = 0; t < 4; ++t) {
#pragma unroll
        for (int h = 0; h < 2; ++h) {
            const float* src = W1g + (h * 32 + quad * 8) * 256 + jb + t * 16 + l16;
            bf16x8 f;
#pragma unroll
            for (int i = 0; i < 8; ++i) f[i] = (__bf16)(src[i * 256] * TS);
            w1f[t * 2 + h] = f;
        }
    }

    // ---------------- ghf per tile: (gh0 .* v) f32 * IVS; C's parked in AGPRs ----
    float ghfA[16], ghfB[16], ghfC[16];   // ghfC values live in acc half
#pragma unroll
    for (int t = 0; t < 4; ++t) {
        const float* wr = W2g + (jb + t * 16 + l16) * 64;
        bf16x8 aw0 = cvt8(*(const f32x4*)(wr + quad * 8),      *(const f32x4*)(wr + quad * 8 + 4));
        bf16x8 aw1 = cvt8(*(const f32x4*)(wr + 32 + quad * 8), *(const f32x4*)(wr + 32 + quad * 8 + 4));
        f32x4 vA = {0.f,0.f,0.f,0.f}, vB = {0.f,0.f,0.f,0.f}, vC = {0.f,0.f,0.f,0.f};
        f32x4 gA = {0.f,0.f,0.f,0.f}, gB = {0.f,0.f,0.f,0.f}, gC = {0.f,0.f,0.f,0.f};
        vA = MFMA16(w1f[t * 2 + 0], aeA0, vA);  vA = MFMA16(w1f[t * 2 + 1], aeA1, vA);
        vB = MFMA16(w1f[t * 2 + 0], aeB0, vB);  vB = MFMA16(w1f[t * 2 + 1], aeB1, vB);
        vC = MFMA16(w1f[t * 2 + 0], aeC0, vC);  vC = MFMA16(w1f[t * 2 + 1], aeC1, vC);
        gA = MFMA16(aw0, aeA0, gA);             gA = MFMA16(aw1, aeA1, gA);
        gB = MFMA16(aw0, aeB0, gB);             gB = MFMA16(aw1, aeB1, gB);
        gC = MFMA16(aw0, aeC0, gC);             gC = MFMA16(aw1, aeC1, gC);
#pragma unroll
        for (int i = 0; i < 4; ++i) {
            ghfA[t * 4 + i] = gA[i] * vA[i] * IVS;
            ghfB[t * 4 + i] = gB[i] * vB[i] * IVS;
            ghfC[t * 4 + i] = to_a(gC[i] * vC[i] * IVS);
        }
    }

    // ---------------- W2^T fragments direct from global (A-op: [m=dout][k=j]) ----
    bf16x8 w2f[8];
#pragma unroll
    for (int c = 0; c < 8; ++c) {
        const float* src = W2g + (c * 32 + quad * 8) * 64 + colb + l16;
        bf16x8 f;
#pragma unroll
        for (int i = 0; i < 8; ++i) f[i] = (__bf16)src[i * 64];
        w2f[c] = f;
    }

    // ---------------- state (lane layout: batch=l16, d=colb+quad*4+rg) ----
    f32x4 zvA = *(const f32x4*)(Yg + rowA * 64 + colb + quad * 4);
    f32x4 zvB = *(const f32x4*)(Yg + rowB * 64 + colb + quad * 4);
    f32x4 zvC = *(const f32x4*)(Yg + rowC * 64 + colb + quad * 4);
    f32x4 bb2 = *(const f32x4*)(b2g + colb + quad * 4);
    const float b1r  = b1g[tid] * TS;              // own j = tid (pre-scaled)
    const float w1tr = W1g[64 * 256 + tid] * TS;   // W1 time row (pre-scaled)

    const float dt = 0.125f;
    float kfA[6][4], kfB[6][4];
    float kfC[6][4];              // values parked in acc half (to_a on write)
    float lppA = 0.f, lppB = 0.f, lppC = 0.f;

    // accessors: A/B direct; C via accvgpr_read
#define KVA(s, g) kfA[s][g]
#define KVB(s, g) kfB[s][g]
#define KVC(s, g) from_a(kfC[s][g])

#define S0E(K, g) 0.f
#define S1E(K, g) (0.2f*K(0,g))
#define S2E(K, g) (0.075f*K(0,g) + 0.225f*K(1,g))
#define S3E(K, g) ((44.f/45.f)*K(0,g) + (-56.f/15.f)*K(1,g) + (32.f/9.f)*K(2,g))
#define S4E(K, g) ((19372.f/6561.f)*K(0,g) + (-25360.f/2187.f)*K(1,g) + \
                   (64448.f/6561.f)*K(2,g) + (-212.f/729.f)*K(3,g))
#define S5E(K, g) ((9017.f/3168.f)*K(0,g) + (-355.f/33.f)*K(1,g) + \
                   (46732.f/5247.f)*K(2,g) + (49.f/176.f)*K(3,g) + \
                   (-5103.f/18656.f)*K(4,g))
#define CBE(K, g) ((35.f/384.f)*K(0,g) + (500.f/1113.f)*K(2,g) + \
                   (125.f/192.f)*K(3,g) + (-2187.f/6784.f)*K(4,g) + \
                   (11.f/84.f)*K(5,g))

#define GHA(i) ghfA[i]
#define GHB(i) ghfB[i]
#define GHC(i) from_a(ghfC[i])

#define MM1T(S, GH, t, DODV) { \
    f32x4 ua = *(const f32x4*)(sBW + jb + (t)*16 + quad * 4); \
    ua = MFMA16(w1f[(t)*2 + 0], a10##S, ua); \
    ua = MFMA16(w1f[(t)*2 + 1], a11##S, ua); \
    float h0 = fast_tanh2(ua[0]), h1 = fast_tanh2(ua[1]); \
    float h2 = fast_tanh2(ua[2]), h3 = fast_tanh2(ua[3]); \
    if (DODV) { \
        dv##S += GH((t)*4 + 0) * (1.f - h0*h0); \
        dv##S += GH((t)*4 + 1) * (1.f - h1*h1); \
        dv##S += GH((t)*4 + 2) * (1.f - h2*h2); \
        dv##S += GH((t)*4 + 3) * (1.f - h3*h3); \
    } \
    bf16x4 hv; hv[0]=(__bf16)h0; hv[1]=(__bf16)h1; hv[2]=(__bf16)h2; hv[3]=(__bf16)h3; \
    *(bf16x4*)(sH##S + l16 * SH_S + jb + (t)*16 + quad * 4) = hv; }

#define MM2C(S, c, acc) { \
    bf16x8 hf = *(const bf16x8*)(sH##S + l16 * SH_S + (c)*32 + quad * 8); \
    acc = MFMA16(w2f[c], hf, acc); }

#define YSTORE(S, SXE, K) { \
    bf16x4 yv; \
    yv[0] = (__bf16)(zv##S[0] + dt * (SXE(K,0))); \
    yv[1] = (__bf16)(zv##S[1] + dt * (SXE(K,1))); \
    yv[2] = (__bf16)(zv##S[2] + dt * (SXE(K,2))); \
    yv[3] = (__bf16)(zv##S[3] + dt * (SXE(K,3))); \
    *(bf16x4*)(sY##S + l16 * SY_S + colb + quad * 4) = yv; }

#define STAGE(st, CTI, DTB, DODV, SXE) { \
    const float ti = t0 + (CTI) * dt; \
    YSTORE(A, SXE, KVA) YSTORE(B, SXE, KVB) YSTORE(C, SXE, KVC) \
    sBW[tid] = b1r + ti * w1tr; \
    __syncthreads();  /* barrier1: sY/sBW */ \
    bf16x8 a10A = *(const bf16x8*)(sYA + l16 * SY_S + quad * 8); \
    bf16x8 a11A = *(const bf16x8*)(sYA + l16 * SY_S + 32 + quad * 8); \
    bf16x8 a10B = *(const bf16x8*)(sYB + l16 * SY_S + quad * 8); \
    bf16x8 a11B = *(const bf16x8*)(sYB + l16 * SY_S + 32 + quad * 8); \
    bf16x8 a10C = *(const bf16x8*)(sYC + l16 * SY_S + quad * 8); \
    bf16x8 a11C = *(const bf16x8*)(sYC + l16 * SY_S + 32 + quad * 8); \
    float dvA = 0.f, dvB = 0.f, dvC = 0.f; \
    MM1T(A,GHA,0,DODV) MM1T(B,GHB,0,DODV) MM1T(C,GHC,0,DODV) \
    MM1T(A,GHA,1,DODV) MM1T(B,GHB,1,DODV) MM1T(C,GHC,1,DODV) \
    MM1T(A,GHA,2,DODV) MM1T(B,GHB,2,DODV) MM1T(C,GHC,2,DODV) \
    MM1T(A,GHA,3,DODV) MM1T(B,GHB,3,DODV) MM1T(C,GHC,3,DODV) \
    __syncthreads();  /* barrier2: sH */ \
    f32x4 faA0 = bb2, faA1 = {0.f,0.f,0.f,0.f}; \
    f32x4 faB0 = bb2, faB1 = {0.f,0.f,0.f,0.f}; \
    f32x4 faC0 = bb2, faC1 = {0.f,0.f,0.f,0.f}; \
    MM2C(A,0,faA0) MM2C(B,0,faB0) MM2C(C,0,faC0) \
    MM2C(A,1,faA1) MM2C(B,1,faB1) MM2C(C,1,faC1) \
    MM2C(A,2,faA0) MM2C(B,2,faB0) MM2C(C,2,faC0) \
    MM2C(A,3,faA1) MM2C(B,3,faB1) MM2C(C,3,faC1) \
    MM2C(A,4,faA0) MM2C(B,4,faB0) MM2C(C,4,faC0) \
    MM2C(A,5,faA1) MM2C(B,5,faB1) MM2C(C,5,faC1) \
    MM2C(A,6,faA0) MM2C(B,6,faB0) MM2C(C,6,faC0) \
    MM2C(A,7,faA1) MM2C(B,7,faB1) MM2C(C,7,faC1) \
    f32x4 faA = faA0 + faA1, faB = faB0 + faB1, faC = faC0 + faC1; \
    kfA[st][0] = faA[0]; kfA[st][1] = faA[1]; kfA[st][2] = faA[2]; kfA[st][3] = faA[3]; \
    kfB[st][0] = faB[0]; kfB[st][1] = faB[1]; kfB[st][2] = faB[2]; kfB[st][3] = faB[3]; \
    kfC[st][0] = to_a(faC[0]); kfC[st][1] = to_a(faC[1]); \
    kfC[st][2] = to_a(faC[2]); kfC[st][3] = to_a(faC[3]); \
    if (DODV) { lppA -= (DTB) * dvA; lppB -= (DTB) * dvB; lppC -= (DTB) * dvC; } }

    for (int step = 0; step < 8; ++step) {
        const float t0 = dt * (float)step;
        STAGE(0, 0.f,     dt*(35.f/384.f),    1, S0E)
        STAGE(1, 0.2f,    0.f,                0, S1E)
        STAGE(2, 0.3f,    dt*(500.f/1113.f),  1, S2E)
        STAGE(3, 0.8f,    dt*(125.f/192.f),   1, S3E)
        STAGE(4, 8.f/9.f, dt*(-2187.f/6784.f),1, S4E)
        STAGE(5, 1.f,     dt*(11.f/84.f),     1, S5E)
        zvA[0] += dt * CBE(KVA,0);  zvA[1] += dt * CBE(KVA,1);
        zvA[2] += dt * CBE(KVA,2);  zvA[3] += dt * CBE(KVA,3);
        zvB[0] += dt * CBE(KVB,0);  zvB[1] += dt * CBE(KVB,1);
        zvB[2] += dt * CBE(KVB,2);  zvB[3] += dt * CBE(KVB,3);
        zvC[0] += dt * CBE(KVC,0);  zvC[1] += dt * CBE(KVC,1);
        zvC[2] += dt * CBE(KVC,2);  zvC[3] += dt * CBE(KVC,3);
    }

    // ---------------- epilogue ----------------
    *(f32x4*)(Og + rowA * 64 + colb + quad * 4) = zvA;
    *(f32x4*)(Og + rowB * 64 + colb + quad * 4) = zvB;
    *(f32x4*)(Og + rowC * 64 + colb + quad * 4) = zvC;   // clamped row: same-value dup
    float ssA = zvA[0]*zvA[0] + zvA[1]*zvA[1] + zvA[2]*zvA[2] + zvA[3]*zvA[3];
    float ssB = zvB[0]*zvB[0] + zvB[1]*zvB[1] + zvB[2]*zvB[2] + zvB[3]*zvB[3];
    float ssC = zvC[0]*zvC[0] + zvC[1]*zvC[1] + zvC[2]*zvC[2] + zvC[3]*zvC[3];
    ssA += __shfl_xor(ssA, 16);  ssA += __shfl_xor(ssA, 32);
    ssB += __shfl_xor(ssB, 16);  ssB += __shfl_xor(ssB, 32);
    ssC += __shfl_xor(ssC, 16);  ssC += __shfl_xor(ssC, 32);
    float lpA = lppA;  lpA += __shfl_xor(lpA, 16);  lpA += __shfl_xor(lpA, 32);
    float lpB = lppB;  lpB += __shfl_xor(lpB, 16);  lpB += __shfl_xor(lpB, 32);
    float lpC = lppC;  lpC += __shfl_xor(lpC, 16);  lpC += __shfl_xor(lpC, 32);
    if (quad == 0) {
        sRedSS[wave * 16 + l16] = ssA;        sRedLP[wave * 16 + l16] = lpA;
        sRedSS[64 + wave * 16 + l16] = ssB;   sRedLP[64 + wave * 16 + l16] = lpB;
        sRedSS[128 + wave * 16 + l16] = ssC;  sRedLP[128 + wave * 16 + l16] = lpC;
    }
    __syncthreads();
    if (tid < 48) {
        const float CLOG = -58.8120661f;  // -32*ln(2*pi)
        int third = tid >> 4, r = tid & 15, base = third * 64;
        float sfull = sRedSS[base + r] + sRedSS[base + 16 + r]
                    + sRedSS[base + 32 + r] + sRedSS[base + 48 + r];
        float lfull = sRedLP[base + r] + sRedLP[base + 16 + r]
                    + sRedLP[base + 32 + r] + sRedLP[base + 48 + r];
        int idx = min(blockIdx.x * 48 + third * 16 + r, 32767);  // clamped: same-value dup
        Og[32768 * 64 + idx] = CLOG - 0.5f * sfull - lfull;
    }
}

extern "C" void kernel_launch(void* const* d_in, const int* in_sizes, int n_in,
                              void* d_out, int out_size, void* d_ws, size_t ws_size,
                              hipStream_t stream) {
    const float* Yg  = (const float*)d_in[0];
    const float* Eg  = (const float*)d_in[1];
    const float* W1g = (const float*)d_in[2];  // [65][256]
    const float* b1g = (const float*)d_in[3];
    const float* W2g = (const float*)d_in[4];  // [256][64]
    const float* b2g = (const float*)d_in[5];
    float* Og = (float*)d_out;                 // z (32768*64) then log_px (32768)
    cnf_kernel<<<dim3(683), dim3(256), 0, stream>>>(Yg, Eg, W1g, b1g, W2g, b2g, Og);
}

// Round 15
// 249.396 us; speedup vs baseline: 2.3053x; 2.3053x over previous
//
#include <hip/hip_runtime.h>

// CNF forward: 8 fixed dopri5 steps x 6 stages, rows independent.
// R20 = R17 restored (best verified: 210us steady, 249.6us harness).
// Design-space map from R6-R19:
//  - >2 waves/EU: spill wall (weights+state ~152-190 regs vs <256 budgets)
//  - weights-in-LDS @ 3 waves/EU: LDS-pipe-bound, 271us (R14)
//  - 2-tile ILP + weights-in-regs @ 2 waves/EU: 210us (R17) <- THIS
//  - 3-tile: 128-arch-half overflow under (256,2)'s fixed split (R18/R19,
//    both directions: plain regs AND AGPR-parking via accvgpr asm)
// R17's content: dual 16-row tiles/block (barriers amortized, 2 indep
// chains fill latency windows); all weight frags in regs (64 acc);
// stride-76/268 LDS (bank conflicts 2.36e7 -> 8192); W1 pre-scaled by
// 2*log2e so tanh = exp2+add+rcp+fma (ghf compensated by ln2/2); raw-f32
// k-values; deferred lp reduction.

typedef __bf16 bf16x8 __attribute__((ext_vector_type(8)));
typedef __bf16 bf16x4 __attribute__((ext_vector_type(4)));
typedef float  f32x4  __attribute__((ext_vector_type(4)));
typedef unsigned int u32;

#define MFMA16(a, b, c) __builtin_amdgcn_mfma_f32_16x16x32_bf16((a), (b), (c), 0, 0, 0)

#define SY_S 76    // sY row stride in bf16 (38 dwords == 6 mod 32)
#define SH_S 268   // sH row stride in bf16 (134 dwords == 6 mod 32)

__device__ __forceinline__ float fast_tanh2(float x2) {   // x2 = 2*log2e*x
    float e = __builtin_amdgcn_exp2f(x2);                 // e^(2x)
    return 1.0f - 2.0f * __builtin_amdgcn_rcpf(e + 1.0f);
}
__device__ __forceinline__ bf16x8 cvt8(f32x4 a, f32x4 b) {
    bf16x8 r;
#pragma unroll
    for (int i = 0; i < 4; ++i) { r[i] = (__bf16)a[i]; r[4 + i] = (__bf16)b[i]; }
    return r;
}

extern "C" __global__ void __launch_bounds__(256, 2)
cnf_kernel(const float* __restrict__ Yg, const float* __restrict__ Eg,
           const float* __restrict__ W1g, const float* __restrict__ b1g,
           const float* __restrict__ W2g, const float* __restrict__ b2g,
           float* __restrict__ Og)
{
    // ---- LDS (~24 KB; 2 blocks/CU at 2 waves/EU) ----
    __shared__ __align__(16) __bf16 sYA[16 * SY_S], sYB[16 * SY_S];
    __shared__ __align__(16) __bf16 sHA[16 * SH_S], sHB[16 * SH_S];
    __shared__ float sBW[256];                      // per-stage (b1 + t*W1_t) * 2log2e
    __shared__ float sRedSS[128], sRedLP[128];

    const int tid  = threadIdx.x;
    const int wave = tid >> 6;        // 0..3
    const int lane = tid & 63;
    const int quad = lane >> 4;
    const int l16  = lane & 15;
    const int colb = wave * 16;       // own output-col tile base
    const int jb   = wave * 64;       // own hidden-j base
    const int rowA = blockIdx.x * 32 + l16;   // tile A batch row
    const int rowB = rowA + 16;               // tile B batch row

    const float TS  = 2.885390081777927f;    // 2*log2(e)
    const float IVS = 0.346573590279973f;    // ln(2)/2 = 1/TS

    // ---------------- e fragments (both tiles) ----------------
    bf16x8 aeA0, aeA1, aeB0, aeB1;
    {
        const float* eA = Eg + rowA * 64;
        const float* eB = Eg + rowB * 64;
        aeA0 = cvt8(*(const f32x4*)(eA + quad * 8),      *(const f32x4*)(eA + quad * 8 + 4));
        aeA1 = cvt8(*(const f32x4*)(eA + 32 + quad * 8), *(const f32x4*)(eA + 32 + quad * 8 + 4));
        aeB0 = cvt8(*(const f32x4*)(eB + quad * 8),      *(const f32x4*)(eB + quad * 8 + 4));
        aeB1 = cvt8(*(const f32x4*)(eB + 32 + quad * 8), *(const f32x4*)(eB + 32 + quad * 8 + 4));
    }

    // ---------------- W1 fragments, PRE-SCALED by TS (A-op: [m=j][k=d]) ----
    bf16x8 w1f[8];
#pragma unroll
    for (int t = 0; t < 4; ++t) {
#pragma unroll
        for (int h = 0; h < 2; ++h) {
            const float* src = W1g + (h * 32 + quad * 8) * 256 + jb + t * 16 + l16;
            bf16x8 f;
#pragma unroll
            for (int i = 0; i < 8; ++i) f[i] = (__bf16)(src[i * 256] * TS);
            w1f[t * 2 + h] = f;
        }
    }

    // ---------------- ghf per tile: (gh0 .* v) f32 * IVS (undo W1 scale) ----
    // v^T = (e@W1a_scaled)^T via operand swap = TS*(e@W1a)^T
    float ghfA[16], ghfB[16];
#pragma unroll
    for (int t = 0; t < 4; ++t) {
        const float* wr = W2g + (jb + t * 16 + l16) * 64;
        bf16x8 aw0 = cvt8(*(const f32x4*)(wr + quad * 8),      *(const f32x4*)(wr + quad * 8 + 4));
        bf16x8 aw1 = cvt8(*(const f32x4*)(wr + 32 + quad * 8), *(const f32x4*)(wr + 32 + quad * 8 + 4));
        f32x4 vA = {0.f,0.f,0.f,0.f}, vB = {0.f,0.f,0.f,0.f};
        f32x4 gA = {0.f,0.f,0.f,0.f}, gB = {0.f,0.f,0.f,0.f};
        vA = MFMA16(w1f[t * 2 + 0], aeA0, vA);  vA = MFMA16(w1f[t * 2 + 1], aeA1, vA);
        vB = MFMA16(w1f[t * 2 + 0], aeB0, vB);  vB = MFMA16(w1f[t * 2 + 1], aeB1, vB);
        gA = MFMA16(aw0, aeA0, gA);             gA = MFMA16(aw1, aeA1, gA);
        gB = MFMA16(aw0, aeB0, gB);             gB = MFMA16(aw1, aeB1, gB);
#pragma unroll
        for (int i = 0; i < 4; ++i) {
            ghfA[t * 4 + i] = gA[i] * vA[i] * IVS;
            ghfB[t * 4 + i] = gB[i] * vB[i] * IVS;
        }
    }

    // ---------------- W2^T fragments direct from global (A-op: [m=dout][k=j]) ----
    bf16x8 w2f[8];
#pragma unroll
    for (int c = 0; c < 8; ++c) {
        const float* src = W2g + (c * 32 + quad * 8) * 64 + colb + l16;
        bf16x8 f;
#pragma unroll
        for (int i = 0; i < 8; ++i) f[i] = (__bf16)src[i * 64];
        w2f[c] = f;
    }

    // ---------------- state (lane layout: batch=l16, d=colb+quad*4+rg) ----
    f32x4 zvA = *(const f32x4*)(Yg + rowA * 64 + colb + quad * 4);
    f32x4 zvB = *(const f32x4*)(Yg + rowB * 64 + colb + quad * 4);
    f32x4 bb2 = *(const f32x4*)(b2g + colb + quad * 4);
    const float b1r  = b1g[tid] * TS;              // own j = tid (pre-scaled)
    const float w1tr = W1g[64 * 256 + tid] * TS;   // W1 time row (pre-scaled)

    const float dt = 0.125f;
    float kfA[6][4], kfB[6][4];   // k_dz in raw f32
    float lppA = 0.f, lppB = 0.f;

#define S0X(arr, g) 0.f
#define S1X(arr, g) (0.2f*arr[0][g])
#define S2X(arr, g) (0.075f*arr[0][g] + 0.225f*arr[1][g])
#define S3X(arr, g) ((44.f/45.f)*arr[0][g] + (-56.f/15.f)*arr[1][g] + (32.f/9.f)*arr[2][g])
#define S4X(arr, g) ((19372.f/6561.f)*arr[0][g] + (-25360.f/2187.f)*arr[1][g] + \
                     (64448.f/6561.f)*arr[2][g] + (-212.f/729.f)*arr[3][g])
#define S5X(arr, g) ((9017.f/3168.f)*arr[0][g] + (-355.f/33.f)*arr[1][g] + \
                     (46732.f/5247.f)*arr[2][g] + (49.f/176.f)*arr[3][g] + \
                     (-5103.f/18656.f)*arr[4][g])
#define CBX(arr, g) ((35.f/384.f)*arr[0][g] + (500.f/1113.f)*arr[2][g] + \
                     (125.f/192.f)*arr[3][g] + (-2187.f/6784.f)*arr[4][g] + \
                     (11.f/84.f)*arr[5][g])

    // matmul-1 tile (per data-tile S, j-tile t); ua is pre-scaled by TS
#define MM1T(S, t, DODV) { \
    f32x4 ua = *(const f32x4*)(sBW + jb + (t)*16 + quad * 4); \
    ua = MFMA16(w1f[(t)*2 + 0], a10##S, ua); \
    ua = MFMA16(w1f[(t)*2 + 1], a11##S, ua); \
    float h0 = fast_tanh2(ua[0]), h1 = fast_tanh2(ua[1]); \
    float h2 = fast_tanh2(ua[2]), h3 = fast_tanh2(ua[3]); \
    if (DODV) { \
        dv##S += ghf##S[(t)*4 + 0] * (1.f - h0*h0); \
        dv##S += ghf##S[(t)*4 + 1] * (1.f - h1*h1); \
        dv##S += ghf##S[(t)*4 + 2] * (1.f - h2*h2); \
        dv##S += ghf##S[(t)*4 + 3] * (1.f - h3*h3); \
    } \
    bf16x4 hv; hv[0]=(__bf16)h0; hv[1]=(__bf16)h1; hv[2]=(__bf16)h2; hv[3]=(__bf16)h3; \
    *(bf16x4*)(sH##S + l16 * SH_S + jb + (t)*16 + quad * 4) = hv; }

#define MM2C(S, c, acc) { \
    bf16x8 hf = *(const bf16x8*)(sH##S + l16 * SH_S + (c)*32 + quad * 8); \
    acc = MFMA16(w2f[c], hf, acc); }

#define STAGE(st, CTI, DTB, DODV, SX) { \
    const float ti = t0 + (CTI) * dt; \
    { bf16x4 yv; \
      yv[0] = (__bf16)(zvA[0] + dt * (SX(kfA,0))); \
      yv[1] = (__bf16)(zvA[1] + dt * (SX(kfA,1))); \
      yv[2] = (__bf16)(zvA[2] + dt * (SX(kfA,2))); \
      yv[3] = (__bf16)(zvA[3] + dt * (SX(kfA,3))); \
      *(bf16x4*)(sYA + l16 * SY_S + colb + quad * 4) = yv; } \
    { bf16x4 yv; \
      yv[0] = (__bf16)(zvB[0] + dt * (SX(kfB,0))); \
      yv[1] = (__bf16)(zvB[1] + dt * (SX(kfB,1))); \
      yv[2] = (__bf16)(zvB[2] + dt * (SX(kfB,2))); \
      yv[3] = (__bf16)(zvB[3] + dt * (SX(kfB,3))); \
      *(bf16x4*)(sYB + l16 * SY_S + colb + quad * 4) = yv; } \
    sBW[tid] = b1r + ti * w1tr; \
    __syncthreads();  /* barrier1: sY/sBW */ \
    bf16x8 a10A = *(const bf16x8*)(sYA + l16 * SY_S + quad * 8); \
    bf16x8 a11A = *(const bf16x8*)(sYA + l16 * SY_S + 32 + quad * 8); \
    bf16x8 a10B = *(const bf16x8*)(sYB + l16 * SY_S + quad * 8); \
    bf16x8 a11B = *(const bf16x8*)(sYB + l16 * SY_S + 32 + quad * 8); \
    float dvA = 0.f, dvB = 0.f; \
    MM1T(A,0,DODV) MM1T(B,0,DODV) MM1T(A,1,DODV) MM1T(B,1,DODV) \
    MM1T(A,2,DODV) MM1T(B,2,DODV) MM1T(A,3,DODV) MM1T(B,3,DODV) \
    __syncthreads();  /* barrier2: sH */ \
    f32x4 faA0 = bb2, faA1 = {0.f,0.f,0.f,0.f}; \
    f32x4 faB0 = bb2, faB1 = {0.f,0.f,0.f,0.f}; \
    MM2C(A,0,faA0) MM2C(B,0,faB0) MM2C(A,1,faA1) MM2C(B,1,faB1) \
    MM2C(A,2,faA0) MM2C(B,2,faB0) MM2C(A,3,faA1) MM2C(B,3,faB1) \
    MM2C(A,4,faA0) MM2C(B,4,faB0) MM2C(A,5,faA1) MM2C(B,5,faB1) \
    MM2C(A,6,faA0) MM2C(B,6,faB0) MM2C(A,7,faA1) MM2C(B,7,faB1) \
    f32x4 faA = faA0 + faA1, faB = faB0 + faB1; \
    kfA[st][0] = faA[0]; kfA[st][1] = faA[1]; kfA[st][2] = faA[2]; kfA[st][3] = faA[3]; \
    kfB[st][0] = faB[0]; kfB[st][1] = faB[1]; kfB[st][2] = faB[2]; kfB[st][3] = faB[3]; \
    if (DODV) { lppA -= (DTB) * dvA; lppB -= (DTB) * dvB; } }

    for (int step = 0; step < 8; ++step) {
        const float t0 = dt * (float)step;
        STAGE(0, 0.f,     dt*(35.f/384.f),    1, S0X)
        STAGE(1, 0.2f,    0.f,                0, S1X)
        STAGE(2, 0.3f,    dt*(500.f/1113.f),  1, S2X)
        STAGE(3, 0.8f,    dt*(125.f/192.f),   1, S3X)
        STAGE(4, 8.f/9.f, dt*(-2187.f/6784.f),1, S4X)
        STAGE(5, 1.f,     dt*(11.f/84.f),     1, S5X)
        zvA[0] += dt * CBX(kfA,0);  zvA[1] += dt * CBX(kfA,1);
        zvA[2] += dt * CBX(kfA,2);  zvA[3] += dt * CBX(kfA,3);
        zvB[0] += dt * CBX(kfB,0);  zvB[1] += dt * CBX(kfB,1);
        zvB[2] += dt * CBX(kfB,2);  zvB[3] += dt * CBX(kfB,3);
    }

    // ---------------- epilogue ----------------
    *(f32x4*)(Og + rowA * 64 + colb + quad * 4) = zvA;
    *(f32x4*)(Og + rowB * 64 + colb + quad * 4) = zvB;
    float ssA = zvA[0]*zvA[0] + zvA[1]*zvA[1] + zvA[2]*zvA[2] + zvA[3]*zvA[3];
    float ssB = zvB[0]*zvB[0] + zvB[1]*zvB[1] + zvB[2]*zvB[2] + zvB[3]*zvB[3];
    ssA += __shfl_xor(ssA, 16);  ssA += __shfl_xor(ssA, 32);
    ssB += __shfl_xor(ssB, 16);  ssB += __shfl_xor(ssB, 32);
    float lpA = lppA;  lpA += __shfl_xor(lpA, 16);  lpA += __shfl_xor(lpA, 32);
    float lpB = lppB;  lpB += __shfl_xor(lpB, 16);  lpB += __shfl_xor(lpB, 32);
    if (quad == 0) {
        sRedSS[wave * 16 + l16] = ssA;       sRedLP[wave * 16 + l16] = lpA;
        sRedSS[64 + wave * 16 + l16] = ssB;  sRedLP[64 + wave * 16 + l16] = lpB;
    }
    __syncthreads();
    if (tid < 32) {
        const float CLOG = -58.8120661f;  // -32*ln(2*pi)
        int half = tid >> 4, r = tid & 15, base = half * 64;
        float sfull = sRedSS[base + r] + sRedSS[base + 16 + r]
                    + sRedSS[base + 32 + r] + sRedSS[base + 48 + r];
        float lfull = sRedLP[base + r] + sRedLP[base + 16 + r]
                    + sRedLP[base + 32 + r] + sRedLP[base + 48 + r];
        Og[32768 * 64 + blockIdx.x * 32 + half * 16 + r] = CLOG - 0.5f * sfull - lfull;
    }
}

extern "C" void kernel_launch(void* const* d_in, const int* in_sizes, int n_in,
                              void* d_out, int out_size, void* d_ws, size_t ws_size,
                              hipStream_t stream) {
    const float* Yg  = (const float*)d_in[0];
    const float* Eg  = (const float*)d_in[1];
    const float* W1g = (const float*)d_in[2];  // [65][256]
    const float* b1g = (const float*)d_in[3];
    const float* W2g = (const float*)d_in[4];  // [256][64]
    const float* b2g = (const float*)d_in[5];
    float* Og = (float*)d_out;                 // z (32768*64) then log_px (32768)
    cnf_kernel<<<dim3(1024), dim3(256), 0, stream>>>(Yg, Eg, W1g, b1g, W2g, b2g, Og);
}